// Round 3
// baseline (406.791 us; speedup 1.0000x reference)
//
#include <hip/hip_runtime.h>

typedef __bf16 bf16x8 __attribute__((ext_vector_type(8)));
typedef __bf16 bf16x4 __attribute__((ext_vector_type(4)));
typedef float  f32x4  __attribute__((ext_vector_type(4)));

// Shapes: B=64, C=256, T=128, V=25, K=3, G=4, Cg=64, dk=16
// ws layout: xm f32 @0 (1,638,400 B) | afull bf16 @1,638,400 (393,216 B)
//            wcb bf16 @2,031,616 (98,304 B) | xpad bf16 @2,129,920 (134,217,728 B)

// ===================== FAST PATH =====================

// ---- Kernel 1 (fast): temporal mean + xpad emit ----
// block = (b, c8: 8 channels). Each lane owns a contiguous 400B run (4 t-rows)
// of one channel -> 25 aligned f32x4 loads, static mod-25 accumulation,
// bf16 repack -> xpad[b][c][t][32] (v>=25 zeroed).
__global__ __launch_bounds__(256, 6)
void k_tmean_fast(const float* __restrict__ x, float* __restrict__ xm,
                  __bf16* __restrict__ xpad)
{
    const int bid = blockIdx.x;            // b*32 + c8
    const int b = bid >> 5, c8 = bid & 31;
    const int tid = threadIdx.x;
    const int lane = tid & 63, half = lane >> 5, l32 = lane & 31;
    const int c = c8 * 8 + (tid >> 6) * 2 + half;
    const float* base = x + (size_t)(b * 256 + c) * 3200 + l32 * 100;
    __bf16* xpb = xpad + ((size_t)(b * 256 + c) * 128 + l32 * 4) * 32;

    float acc[25];
#pragma unroll
    for (int j = 0; j < 25; ++j) acc[j] = 0.f;
    f32x4 vv[25];

#pragma unroll
    for (int dt = 0; dt < 4; ++dt) {
        const int i_lo = (dt == 0) ? 0 : 6 * dt + 1;   // rolling window: row dt uses vv[6dt..6dt+6]
#pragma unroll
        for (int i = i_lo; i <= 6 * dt + 6; ++i) {
            vv[i] = *(const f32x4*)(base + i * 4);
#pragma unroll
            for (int e = 0; e < 4; ++e) acc[(4 * i + e) % 25] += vv[i][e];
        }
#pragma unroll
        for (int q = 0; q < 4; ++q) {
            bf16x8 h;
#pragma unroll
            for (int e2 = 0; e2 < 8; ++e2) {
                const int v = q * 8 + e2;
                if (v < 25) { const int f = dt * 25 + v; h[e2] = (__bf16)vv[f >> 2][f & 3]; }
                else        h[e2] = (__bf16)0.f;
            }
            *(bf16x8*)(xpb + dt * 32 + q * 8) = h;
        }
    }

    __shared__ float part[256][26];
#pragma unroll
    for (int j = 0; j < 25; ++j) part[tid][j] = acc[j];
    __syncthreads();
    if (tid < 200) {
        const int cl = tid / 25, v = tid - cl * 25;
        const int src = (cl >> 1) * 64 + (cl & 1) * 32;
        float s = 0.f;
#pragma unroll
        for (int k = 0; k < 32; ++k) s += part[src + k][v];
        xm[((size_t)(b * 256) + c8 * 8 + cl) * 25 + v] = s * (1.0f / 128.0f);
    }
}

// ---- Kernel 2: A_dyn + Afull tables + Wconv->bf16 (one block per b) ----
__global__ __launch_bounds__(256)
void k_adyn(const float* __restrict__ xm, const float* __restrict__ A,
            const float* __restrict__ Wq, const float* __restrict__ Wk,
            const float* __restrict__ alpha, __bf16* __restrict__ afull,
            const float* __restrict__ Wconv, __bf16* __restrict__ wcb)
{
    const int b = blockIdx.x, tid = threadIdx.x;
    __shared__ float xm_s[256 * 25];
    __shared__ float q_s[64 * 25];
    __shared__ float k_s[64 * 25];
    __shared__ float sm_s[4][25][25];
    __shared__ float ad_s[25][25];
    __shared__ float rs_s[3][25];

    // convert this block's 1/64 slice of Wconv to bf16
    for (int i = tid; i < 768; i += 256)
        wcb[b * 768 + i] = (__bf16)Wconv[b * 768 + i];

    for (int i = tid; i < 256 * 25; i += 256) xm_s[i] = xm[(size_t)b * 6400 + i];
    for (int i = tid; i < 75; i += 256) {
        int k3 = i / 25, v = i - (i / 25) * 25;
        float s = 0.f;
        for (int w = 0; w < 25; ++w) s += A[(k3 * 25 + v) * 25 + w];
        rs_s[k3][v] = fmaxf(s, 1e-6f);
    }
    __syncthreads();

    for (int i = tid; i < 1600; i += 256) {
        int o = i / 25, v = i - o * 25;
        const float* wq = Wq + o * 256;
        const float* wk = Wk + o * 256;
        float aq = 0.f, ak = 0.f;
        for (int c = 0; c < 256; ++c) {
            float xv = xm_s[c * 25 + v];
            aq += wq[c] * xv;
            ak += wk[c] * xv;
        }
        q_s[i] = aq; k_s[i] = ak;
    }
    __syncthreads();

    if (tid < 100) {
        int g = tid / 25, v = tid - (tid / 25) * 25;
        float l[25];
#pragma unroll
        for (int w = 0; w < 25; ++w) {
            float s = 0.f;
#pragma unroll
            for (int d = 0; d < 16; ++d)
                s += q_s[(g * 16 + d) * 25 + v] * k_s[(g * 16 + d) * 25 + w];
            l[w] = s * 0.25f;
        }
        float mx = l[0];
#pragma unroll
        for (int w = 1; w < 25; ++w) mx = fmaxf(mx, l[w]);
        float den = 0.f;
#pragma unroll
        for (int w = 0; w < 25; ++w) { l[w] = expf(l[w] - mx); den += l[w]; }
        float rden = 1.f / den;
#pragma unroll
        for (int w = 0; w < 25; ++w) sm_s[g][v][w] = l[w] * rden;
    }
    __syncthreads();
    for (int i = tid; i < 625; i += 256) {
        int v = i / 25, w = i - (i / 25) * 25;
        ad_s[v][w] = 0.25f * (sm_s[0][v][w] + sm_s[1][v][w] + sm_s[2][v][w] + sm_s[3][v][w]);
    }
    __syncthreads();

    const float al = tanhf(alpha[0]);
    for (int i = tid; i < 3 * 32 * 32; i += 256) {
        int k3 = i >> 10, rem = i & 1023, v = rem >> 5, w = rem & 31;
        float val = 0.f;
        if (v < 25 && w < 25)
            val = A[(k3 * 25 + v) * 25 + w] / rs_s[k3][v] + al * ad_s[v][w];
        afull[(size_t)b * 3072 + i] = (__bf16)val;
    }
}

// ---- Kernel 3 (fast): agg MFMA -> xagg LDS -> conv MFMA -> BN + residual ----
// block = (b, g, tt of 4 t). Frags + residual straight from xpad (aligned).
// LDS = xagg[112][64] bf16 only (14.3 KB), col XOR-swizzled by ((cc&7)<<3).
__global__ __launch_bounds__(256, 5)
void k_main_fast(const __bf16* __restrict__ xpad, const __bf16* __restrict__ wcb,
                 const __bf16* __restrict__ afull,
                 const float* __restrict__ gamma, const float* __restrict__ beta,
                 const float* __restrict__ rmean, const float* __restrict__ rvar,
                 float* __restrict__ out)
{
    const int bid = blockIdx.x;
    const int tt = bid & 31;
    const int g  = (bid >> 5) & 3;
    const int b  = bid >> 7;
    const int tid = threadIdx.x;
    const int wave = tid >> 6, lane = tid & 63, l15 = lane & 15, lg = lane >> 4;

    __shared__ __bf16 xagg[112 * 64];    // 14.3 KB

    // A-frags: lane (l15,lg) = x[c=m*16+l15][t=tt*4+wave][v=lg*8..+7], one 16B load each
    const __bf16* xp = xpad + ((size_t)((b * 256 + g * 64) * 128) + tt * 4 + wave) * 32;
    bf16x8 xfrag[4];
#pragma unroll
    for (int m = 0; m < 4; ++m)
        xfrag[m] = *(const bf16x8*)(xp + (size_t)(m * 16 + l15) * 4096 + lg * 8);

    const int o_lane = (wave << 4) + l15;
    const int ch = (g << 6) + o_lane;
    const float inv  = gamma[ch] / sqrtf(rvar[ch] + 1e-5f);
    const float bias = beta[ch] - rmean[ch] * inv;

    // rolling prefetch: Afull B-frags + Wconv bf16 frags
    const __bf16* ab = afull + ((size_t)(b * 3) << 10) + l15 * 32 + lg * 8;
    const __bf16* wb = wcb + (size_t)(g * 64 + o_lane) * 64 + lg * 8;
    bf16x8 bAc[2], bAn[2], wfc[2], wfn[2];
    bAn[0] = *(const bf16x8*)(ab);
    bAn[1] = *(const bf16x8*)(ab + 16 * 32);
    wfn[0] = *(const bf16x8*)(wb);
    wfn[1] = *(const bf16x8*)(wb + 32);

    f32x4 acc[7];
#pragma unroll
    for (int i = 0; i < 7; ++i) acc[i] = (f32x4){0.f, 0.f, 0.f, 0.f};
    const f32x4 zero4 = {0.f, 0.f, 0.f, 0.f};

#pragma unroll
    for (int k3 = 0; k3 < 3; ++k3) {
        bAc[0] = bAn[0]; bAc[1] = bAn[1];
        wfc[0] = wfn[0]; wfc[1] = wfn[1];
        if (k3 < 2) {
            const __bf16* ab2 = ab + (size_t)(k3 + 1) * 1024;
            bAn[0] = *(const bf16x8*)(ab2);
            bAn[1] = *(const bf16x8*)(ab2 + 16 * 32);
            const __bf16* wb2 = wb + (size_t)(k3 + 1) * 16384;
            wfn[0] = *(const bf16x8*)(wb2);
            wfn[1] = *(const bf16x8*)(wb2 + 32);
        }
        if (k3 > 0) __syncthreads();     // prev conv reads done before overwrite

        // aggregation: D[(t=wave, c-tile m), v] -> xagg (swizzled bf16)
#pragma unroll
        for (int m = 0; m < 4; ++m) {
#pragma unroll
            for (int n = 0; n < 2; ++n) {
                f32x4 d = __builtin_amdgcn_mfma_f32_16x16x32_bf16(xfrag[m], bAc[n],
                                                                  zero4, 0, 0, 0);
                const int v = n * 16 + l15;
                if (v < 25) {
                    const int cc  = wave * 25 + v;
                    const int col = (m * 16 + lg * 4) ^ ((cc & 7) << 3);
                    bf16x4 h;
                    h[0] = (__bf16)d[0]; h[1] = (__bf16)d[1];
                    h[2] = (__bf16)d[2]; h[3] = (__bf16)d[3];
                    *(bf16x4*)((char*)xagg + cc * 128 + col * 2) = h;
                }
            }
        }
        __syncthreads();

        // conv: acc[cc-tile, o] += xagg[cc, c] * W[o, c]
#pragma unroll
        for (int mcc = 0; mcc < 7; ++mcc) {
            const int cc = mcc * 16 + l15;
            const int sw2 = (cc & 7) << 3;
#pragma unroll
            for (int ks = 0; ks < 2; ++ks) {
                const int col = (ks * 32 + lg * 8) ^ sw2;
                bf16x8 aF = *(const bf16x8*)((char*)xagg + cc * 128 + col * 2);
                acc[mcc] = __builtin_amdgcn_mfma_f32_16x16x32_bf16(aF, wfc[ks],
                                                                   acc[mcc], 0, 0, 0);
            }
        }
    }

    // epilogue: out = x + acc*inv + bias; residual from xpad (L1/L2-hot, same lines as frags)
    const __bf16* xr = xpad + ((size_t)(b * 256 + ch) * 128 + tt * 4) * 32;
    float* op = out + (size_t)(b * 256 + ch) * 3200 + tt * 100;
#pragma unroll
    for (int mcc = 0; mcc < 7; ++mcc) {
        const int cc0 = (mcc << 4) + (lg << 2);
        if (cc0 < 100) {
            f32x4 o4;
#pragma unroll
            for (int j = 0; j < 4; ++j) {
                const int cc = cc0 + j;
                const int t = cc / 25, v = cc - t * 25;
                o4[j] = (float)xr[t * 32 + v] + acc[mcc][j] * inv + bias;
            }
            *(f32x4*)(op + cc0) = o4;
        }
    }
}

// ===================== SLOW PATH (fallback if ws too small) =====================

__global__ __launch_bounds__(256)
void k_tmean_slow(const float* __restrict__ x, float* __restrict__ xm)
{
    const int bid = blockIdx.x;
    const int b = bid >> 7, c2 = bid & 127;
    const int tid = threadIdx.x;
    const int c_loc = tid >> 7, t = tid & 127;
    const int c = c2 * 2 + c_loc;
    const float* p = x + ((size_t)(b * 256 + c) * 128 + t) * 25;
    float v[25];
#pragma unroll
    for (int j = 0; j < 25; ++j) v[j] = p[j];
#pragma unroll
    for (int s = 1; s < 64; s <<= 1) {
#pragma unroll
        for (int j = 0; j < 25; ++j) v[j] += __shfl_xor(v[j], s);
    }
    __shared__ float part[4][25];
    if ((tid & 63) == 0) {
#pragma unroll
        for (int j = 0; j < 25; ++j) part[tid >> 6][j] = v[j];
    }
    __syncthreads();
    if (tid < 50) {
        const int cl = tid / 25, j = tid - cl * 25;
        xm[((size_t)(b * 256) + c2 * 2 + cl) * 25 + j] =
            (part[cl * 2][j] + part[cl * 2 + 1][j]) * (1.0f / 128.0f);
    }
}

__global__ __launch_bounds__(256, 4)
void k_main_slow(const float* __restrict__ x, const float* __restrict__ Wconv,
                 const __bf16* __restrict__ afull,
                 const float* __restrict__ gamma, const float* __restrict__ beta,
                 const float* __restrict__ rmean, const float* __restrict__ rvar,
                 float* __restrict__ out)
{
    const int bid = blockIdx.x;
    const int tt = bid & 31;
    const int g  = (bid >> 5) & 3;
    const int b  = bid >> 7;
    const int tid = threadIdx.x;
    const int wave = tid >> 6;
    const int lane = tid & 63;
    const int l15 = lane & 15;
    const int lg  = lane >> 4;

    __shared__ __bf16 xs[64 * 4 * 32];
    __shared__ __bf16 xagg[112 * 64];

    {
        const int c = tid >> 2, t = tid & 3;
        const float* p = x + ((size_t)(b * 256 + g * 64 + c) * 128 + tt * 4 + t) * 25;
        float r[25];
#pragma unroll
        for (int j = 0; j < 25; ++j) r[j] = p[j];
        const int rowg = (c * 4 + t) << 2;
        const int sw = c & 7;
#pragma unroll
        for (int ch = 0; ch < 4; ++ch) {
            bf16x8 h;
#pragma unroll
            for (int e = 0; e < 8; ++e) {
                const int v = ch * 8 + e;
                h[e] = (v < 25) ? (__bf16)r[v] : (__bf16)0.f;
            }
            *(bf16x8*)((char*)xs + (((rowg | ch) ^ sw) << 4)) = h;
        }
    }

    bf16x8 bAf[3][2];
#pragma unroll
    for (int k3 = 0; k3 < 3; ++k3)
#pragma unroll
        for (int n = 0; n < 2; ++n)
            bAf[k3][n] = *(const bf16x8*)(afull + ((size_t)(b * 3 + k3) << 10) +
                                          (n * 16 + l15) * 32 + lg * 8);

    const int o_lane = (wave << 4) + l15;
    f32x4 wff[4];
    {
        const float* wp = Wconv + (size_t)((0 * 4 + g) * 64 + o_lane) * 64 + lg * 8;
        wff[0] = *(const f32x4*)wp;        wff[1] = *(const f32x4*)(wp + 4);
        wff[2] = *(const f32x4*)(wp + 32); wff[3] = *(const f32x4*)(wp + 36);
    }

    const int ch = g * 64 + o_lane;
    const float inv  = gamma[ch] / sqrtf(rvar[ch] + 1e-5f);
    const float bias = beta[ch] - rmean[ch] * inv;

    __syncthreads();

    bf16x8 xfrag[4];
#pragma unroll
    for (int m = 0; m < 4; ++m) {
        const int c = m * 16 + l15;
        xfrag[m] = *(const bf16x8*)((char*)xs +
                      (((((c * 4 + wave) << 2) | lg) ^ (c & 7)) << 4));
    }

    f32x4 acc[7];
#pragma unroll
    for (int i = 0; i < 7; ++i) acc[i] = (f32x4){0.f, 0.f, 0.f, 0.f};
    const f32x4 zero4 = {0.f, 0.f, 0.f, 0.f};
    bf16x8 wfc[2];

#pragma unroll
    for (int k3 = 0; k3 < 3; ++k3) {
#pragma unroll
        for (int ks = 0; ks < 2; ++ks) {
            bf16x8 h;
#pragma unroll
            for (int e = 0; e < 4; ++e) {
                h[e]     = (__bf16)wff[ks * 2][e];
                h[e + 4] = (__bf16)wff[ks * 2 + 1][e];
            }
            wfc[ks] = h;
        }
        if (k3 < 2) {
            const float* wp = Wconv + (size_t)(((k3 + 1) * 4 + g) * 64 + o_lane) * 64 + lg * 8;
            wff[0] = *(const f32x4*)wp;        wff[1] = *(const f32x4*)(wp + 4);
            wff[2] = *(const f32x4*)(wp + 32); wff[3] = *(const f32x4*)(wp + 36);
        }

#pragma unroll
        for (int m = 0; m < 4; ++m) {
#pragma unroll
            for (int n = 0; n < 2; ++n) {
                f32x4 d = __builtin_amdgcn_mfma_f32_16x16x32_bf16(xfrag[m], bAf[k3][n],
                                                                  zero4, 0, 0, 0);
                const int v = n * 16 + l15;
                if (v < 25) {
                    const int cc  = wave * 25 + v;
                    const int col = (m * 16 + lg * 4) ^ ((cc & 7) << 3);
                    bf16x4 h;
                    h[0] = (__bf16)d[0]; h[1] = (__bf16)d[1];
                    h[2] = (__bf16)d[2]; h[3] = (__bf16)d[3];
                    *(bf16x4*)((char*)xagg + cc * 128 + col * 2) = h;
                }
            }
        }
        __syncthreads();

#pragma unroll
        for (int mcc = 0; mcc < 7; ++mcc) {
            const int cc = mcc * 16 + l15;
            const int sw2 = (cc & 7) << 3;
#pragma unroll
            for (int ks = 0; ks < 2; ++ks) {
                const int col = (ks * 32 + lg * 8) ^ sw2;
                bf16x8 aF = *(const bf16x8*)((char*)xagg + cc * 128 + col * 2);
                acc[mcc] = __builtin_amdgcn_mfma_f32_16x16x32_bf16(aF, wfc[ks],
                                                                   acc[mcc], 0, 0, 0);
            }
        }
        if (k3 < 2) __syncthreads();
    }

    const size_t obase = (size_t)(b * 256 + ch) * 3200 + tt * 100;
#pragma unroll
    for (int mcc = 0; mcc < 7; ++mcc) {
        const int cc0 = mcc * 16 + lg * 4;
        if (cc0 < 100) {
            f32x4 o4;
#pragma unroll
            for (int j = 0; j < 4; ++j) {
                const int cc = cc0 + j;
                const int t = cc / 25, v = cc - t * 25;
                const int gr = (((o_lane * 4 + t) << 2) | (v >> 3)) ^ (o_lane & 7);
                const float xr = (float)*(const __bf16*)((char*)xs + (gr << 4) + ((v & 7) << 1));
                o4[j] = xr + acc[mcc][j] * inv + bias;
            }
            *(f32x4*)(out + obase + cc0) = o4;
        }
    }
}

extern "C" void kernel_launch(void* const* d_in, const int* in_sizes, int n_in,
                              void* d_out, int out_size, void* d_ws, size_t ws_size,
                              hipStream_t stream) {
    const float* x     = (const float*)d_in[0];
    const float* A     = (const float*)d_in[1];
    const float* Wq    = (const float*)d_in[2];
    const float* Wk    = (const float*)d_in[3];
    const float* Wconv = (const float*)d_in[4];
    const float* alpha = (const float*)d_in[5];
    const float* gamma = (const float*)d_in[6];
    const float* beta  = (const float*)d_in[7];
    const float* rmean = (const float*)d_in[8];
    const float* rvar  = (const float*)d_in[9];
    float* out = (float*)d_out;

    float*  xm    = (float*)d_ws;
    __bf16* afull = (__bf16*)((char*)d_ws + 1638400);
    __bf16* wcb   = (__bf16*)((char*)d_ws + 2031616);
    __bf16* xpad  = (__bf16*)((char*)d_ws + 2129920);

    const size_t need = 2129920ull + 134217728ull;
    if (ws_size >= need) {
        k_tmean_fast<<<64 * 32, 256, 0, stream>>>(x, xm, xpad);
        k_adyn<<<64, 256, 0, stream>>>(xm, A, Wq, Wk, alpha, afull, Wconv, wcb);
        k_main_fast<<<64 * 4 * 32, 256, 0, stream>>>(xpad, wcb, afull, gamma, beta,
                                                     rmean, rvar, out);
    } else {
        k_tmean_slow<<<64 * 128, 256, 0, stream>>>(x, xm);
        k_adyn<<<64, 256, 0, stream>>>(xm, A, Wq, Wk, alpha, afull, Wconv, wcb);
        k_main_slow<<<64 * 4 * 32, 256, 0, stream>>>(x, Wconv, afull, gamma, beta,
                                                     rmean, rvar, out);
    }
}

// Round 4
// 299.501 us; speedup vs baseline: 1.3582x; 1.3582x over previous
//
#include <hip/hip_runtime.h>

typedef __bf16 bf16x8 __attribute__((ext_vector_type(8)));
typedef __bf16 bf16x4 __attribute__((ext_vector_type(4)));
typedef float  f32x4  __attribute__((ext_vector_type(4)));

// Shapes: B=64, C=256, T=128, V=25, K=3, G=4, Cg=64, dk=16
// ws layout: xm f32 @0 (1,638,400 B) | afull bf16 @1,638,400 (393,216 B)
//            wcb bf16 @2,031,616 (98,304 B) | xpad bf16 @2,129,920 (134,217,728 B)

// ---- Kernel 1: temporal mean + xpad emit (LDS-transposed, aligned loads) ----
// block = (b, c-pair). Phase 1: 1600 aligned f32x4 loads -> LDS (raw layout).
// Phase 2: thread=(c_loc,t) reads its 25-float row from LDS (stride-25 words,
// conflict-free), packs bf16 xpad row, then 64-lane butterfly for the T-mean.
__global__ __launch_bounds__(256)
void k_tmean2(const float* __restrict__ x, float* __restrict__ xm,
              __bf16* __restrict__ xpad)
{
    const int bid = blockIdx.x;            // b*128 + c2
    const int b = bid >> 7, c2 = bid & 127;
    const int c0 = c2 * 2;
    const int tid = threadIdx.x;

    __shared__ float xls[6400];            // 25.6 KB
    const float* gx = x + (size_t)(b * 256 + c0) * 3200;
#pragma unroll
    for (int i = 0; i < 7; ++i) {
        const int idx = i * 256 + tid;
        if (idx < 1600)
            *(f32x4*)(&xls[idx * 4]) = *(const f32x4*)(gx + idx * 4);
    }
    __syncthreads();

    const int c_loc = tid >> 7, t = tid & 127;
    float v[25];
#pragma unroll
    for (int j = 0; j < 25; ++j) v[j] = xls[c_loc * 3200 + t * 25 + j];

    // pack xpad row (must happen BEFORE butterfly mutates v)
    __bf16* xpb = xpad + ((size_t)(b * 256 + c0 + c_loc) * 128 + t) * 32;
#pragma unroll
    for (int q = 0; q < 4; ++q) {
        bf16x8 h;
#pragma unroll
        for (int e = 0; e < 8; ++e) {
            const int ve = q * 8 + e;
            h[e] = (ve < 25) ? (__bf16)v[ve] : (__bf16)0.f;
        }
        *(bf16x8*)(xpb + q * 8) = h;
    }

    // butterfly over the 64 t-lanes of this wave
#pragma unroll
    for (int s = 1; s < 64; s <<= 1) {
#pragma unroll
        for (int j = 0; j < 25; ++j) v[j] += __shfl_xor(v[j], s);
    }
    __shared__ float part[4][25];
    if ((tid & 63) == 0) {
        const int w = tid >> 6;
#pragma unroll
        for (int j = 0; j < 25; ++j) part[w][j] = v[j];
    }
    __syncthreads();
    if (tid < 50) {
        const int cl = tid / 25, j = tid - cl * 25;
        xm[((size_t)(b * 256) + c0 + cl) * 25 + j] =
            (part[cl * 2][j] + part[cl * 2 + 1][j]) * (1.0f / 128.0f);
    }
}

// ---- Kernel 2: A_dyn + Afull tables + Wconv->bf16 (one block per b) ----
__global__ __launch_bounds__(256)
void k_adyn(const float* __restrict__ xm, const float* __restrict__ A,
            const float* __restrict__ Wq, const float* __restrict__ Wk,
            const float* __restrict__ alpha, __bf16* __restrict__ afull,
            const float* __restrict__ Wconv, __bf16* __restrict__ wcb)
{
    const int b = blockIdx.x, tid = threadIdx.x;
    __shared__ float xm_s[256 * 25];
    __shared__ float q_s[64 * 25];
    __shared__ float k_s[64 * 25];
    __shared__ float sm_s[4][25][25];
    __shared__ float ad_s[25][25];
    __shared__ float rs_s[3][25];

    for (int i = tid; i < 768; i += 256)
        wcb[b * 768 + i] = (__bf16)Wconv[b * 768 + i];

    for (int i = tid; i < 256 * 25; i += 256) xm_s[i] = xm[(size_t)b * 6400 + i];
    for (int i = tid; i < 75; i += 256) {
        int k3 = i / 25, v = i - (i / 25) * 25;
        float s = 0.f;
        for (int w = 0; w < 25; ++w) s += A[(k3 * 25 + v) * 25 + w];
        rs_s[k3][v] = fmaxf(s, 1e-6f);
    }
    __syncthreads();

    for (int i = tid; i < 1600; i += 256) {
        int o = i / 25, v = i - o * 25;
        const float* wq = Wq + o * 256;
        const float* wk = Wk + o * 256;
        float aq = 0.f, ak = 0.f;
        for (int c = 0; c < 256; ++c) {
            float xv = xm_s[c * 25 + v];
            aq += wq[c] * xv;
            ak += wk[c] * xv;
        }
        q_s[i] = aq; k_s[i] = ak;
    }
    __syncthreads();

    if (tid < 100) {
        int g = tid / 25, v = tid - (tid / 25) * 25;
        float l[25];
#pragma unroll
        for (int w = 0; w < 25; ++w) {
            float s = 0.f;
#pragma unroll
            for (int d = 0; d < 16; ++d)
                s += q_s[(g * 16 + d) * 25 + v] * k_s[(g * 16 + d) * 25 + w];
            l[w] = s * 0.25f;
        }
        float mx = l[0];
#pragma unroll
        for (int w = 1; w < 25; ++w) mx = fmaxf(mx, l[w]);
        float den = 0.f;
#pragma unroll
        for (int w = 0; w < 25; ++w) { l[w] = expf(l[w] - mx); den += l[w]; }
        float rden = 1.f / den;
#pragma unroll
        for (int w = 0; w < 25; ++w) sm_s[g][v][w] = l[w] * rden;
    }
    __syncthreads();
    for (int i = tid; i < 625; i += 256) {
        int v = i / 25, w = i - (i / 25) * 25;
        ad_s[v][w] = 0.25f * (sm_s[0][v][w] + sm_s[1][v][w] + sm_s[2][v][w] + sm_s[3][v][w]);
    }
    __syncthreads();

    const float al = tanhf(alpha[0]);
    for (int i = tid; i < 3 * 32 * 32; i += 256) {
        int k3 = i >> 10, rem = i & 1023, v = rem >> 5, w = rem & 31;
        float val = 0.f;
        if (v < 25 && w < 25)
            val = A[(k3 * 25 + v) * 25 + w] / rs_s[k3][v] + al * ad_s[v][w];
        afull[(size_t)b * 3072 + i] = (__bf16)val;
    }
}

// ---- Kernel 3: agg MFMA -> xagg LDS -> conv MFMA -> BN + residual ----
// block = (b, g, tt of 4 t). Frags + residual straight from xpad (aligned 16B).
// LDS = xagg[112][64] bf16 (14.3 KB), col XOR-swizzled by ((cc&7)<<3).
// Per-k3 table loads (L2-hot) instead of register double-buffering: no spills.
__global__ __launch_bounds__(256, 4)
void k_main2(const __bf16* __restrict__ xpad, const __bf16* __restrict__ wcb,
             const __bf16* __restrict__ afull,
             const float* __restrict__ gamma, const float* __restrict__ beta,
             const float* __restrict__ rmean, const float* __restrict__ rvar,
             float* __restrict__ out)
{
    const int bid = blockIdx.x;
    const int tt = bid & 31;
    const int g  = (bid >> 5) & 3;
    const int b  = bid >> 7;
    const int tid = threadIdx.x;
    const int wave = tid >> 6, lane = tid & 63, l15 = lane & 15, lg = lane >> 4;

    __shared__ __bf16 xagg[112 * 64];    // 14.3 KB

    // A-frags: lane (l15,lg) = x[c=m*16+l15][t=tt*4+wave][v=lg*8..+7]
    const __bf16* xp = xpad + ((size_t)((b * 256 + g * 64) * 128) + tt * 4 + wave) * 32;
    bf16x8 xfrag[4];
#pragma unroll
    for (int m = 0; m < 4; ++m)
        xfrag[m] = *(const bf16x8*)(xp + (size_t)(m * 16 + l15) * 4096 + lg * 8);

    const int o_lane = (wave << 4) + l15;
    const int ch = (g << 6) + o_lane;
    const float inv  = gamma[ch] / sqrtf(rvar[ch] + 1e-5f);
    const float bias = beta[ch] - rmean[ch] * inv;

    const __bf16* ab = afull + ((size_t)(b * 3) << 10) + l15 * 32 + lg * 8;
    const __bf16* wb = wcb + (size_t)(g * 64 + o_lane) * 64 + lg * 8;

    f32x4 acc[7];
#pragma unroll
    for (int i = 0; i < 7; ++i) acc[i] = (f32x4){0.f, 0.f, 0.f, 0.f};
    const f32x4 zero4 = {0.f, 0.f, 0.f, 0.f};

#pragma unroll
    for (int k3 = 0; k3 < 3; ++k3) {
        bf16x8 bA[2], wf[2];
        bA[0] = *(const bf16x8*)(ab + (size_t)k3 * 1024);
        bA[1] = *(const bf16x8*)(ab + (size_t)k3 * 1024 + 16 * 32);
        wf[0] = *(const bf16x8*)(wb + (size_t)k3 * 16384);
        wf[1] = *(const bf16x8*)(wb + (size_t)k3 * 16384 + 32);

        if (k3 > 0) __syncthreads();     // prev conv reads done before overwrite

        // aggregation: D[(t=wave, c-tile m), v] -> xagg (swizzled bf16)
#pragma unroll
        for (int m = 0; m < 4; ++m) {
#pragma unroll
            for (int n = 0; n < 2; ++n) {
                f32x4 d = __builtin_amdgcn_mfma_f32_16x16x32_bf16(xfrag[m], bA[n],
                                                                  zero4, 0, 0, 0);
                const int v = n * 16 + l15;
                if (v < 25) {
                    const int cc  = wave * 25 + v;
                    const int col = (m * 16 + lg * 4) ^ ((cc & 7) << 3);
                    bf16x4 h;
                    h[0] = (__bf16)d[0]; h[1] = (__bf16)d[1];
                    h[2] = (__bf16)d[2]; h[3] = (__bf16)d[3];
                    *(bf16x4*)((char*)xagg + cc * 128 + col * 2) = h;
                }
            }
        }
        __syncthreads();

        // conv: acc[cc-tile, o] += xagg[cc, c] * W[o, c]
#pragma unroll
        for (int mcc = 0; mcc < 7; ++mcc) {
            const int cc = mcc * 16 + l15;
            const int sw2 = (cc & 7) << 3;
#pragma unroll
            for (int ks = 0; ks < 2; ++ks) {
                const int col = (ks * 32 + lg * 8) ^ sw2;
                bf16x8 aF = *(const bf16x8*)((char*)xagg + cc * 128 + col * 2);
                acc[mcc] = __builtin_amdgcn_mfma_f32_16x16x32_bf16(aF, wf[ks],
                                                                   acc[mcc], 0, 0, 0);
            }
        }
    }

    // epilogue: out = x + acc*inv + bias; residual from xpad (L1-hot: same lines as frags)
    const __bf16* xr = xpad + ((size_t)(b * 256 + ch) * 128 + tt * 4) * 32;
    float* op = out + (size_t)(b * 256 + ch) * 3200 + tt * 100;
#pragma unroll
    for (int mcc = 0; mcc < 7; ++mcc) {
        const int cc0 = (mcc << 4) + (lg << 2);
        if (cc0 < 100) {
            f32x4 o4;
#pragma unroll
            for (int j = 0; j < 4; ++j) {
                const int cc = cc0 + j;
                const int t = cc / 25, v = cc - t * 25;
                o4[j] = (float)xr[t * 32 + v] + acc[mcc][j] * inv + bias;
            }
            *(f32x4*)(op + cc0) = o4;
        }
    }
}

extern "C" void kernel_launch(void* const* d_in, const int* in_sizes, int n_in,
                              void* d_out, int out_size, void* d_ws, size_t ws_size,
                              hipStream_t stream) {
    const float* x     = (const float*)d_in[0];
    const float* A     = (const float*)d_in[1];
    const float* Wq    = (const float*)d_in[2];
    const float* Wk    = (const float*)d_in[3];
    const float* Wconv = (const float*)d_in[4];
    const float* alpha = (const float*)d_in[5];
    const float* gamma = (const float*)d_in[6];
    const float* beta  = (const float*)d_in[7];
    const float* rmean = (const float*)d_in[8];
    const float* rvar  = (const float*)d_in[9];
    float* out = (float*)d_out;

    float*  xm    = (float*)d_ws;
    __bf16* afull = (__bf16*)((char*)d_ws + 1638400);
    __bf16* wcb   = (__bf16*)((char*)d_ws + 2031616);
    __bf16* xpad  = (__bf16*)((char*)d_ws + 2129920);

    k_tmean2<<<64 * 128, 256, 0, stream>>>(x, xm, xpad);
    k_adyn<<<64, 256, 0, stream>>>(xm, A, Wq, Wk, alpha, afull, Wconv, wcb);
    k_main2<<<64 * 4 * 32, 256, 0, stream>>>(xpad, wcb, afull, gamma, beta,
                                             rmean, rvar, out);
}